// Round 2
// baseline (1180.554 us; speedup 1.0000x reference)
//
#include <hip/hip_runtime.h>
#include <hip/hip_fp16.h>
#include <math.h>

// B=32, N=1024 Sinkhorn (20 iters). scores@W+b cancels under the first row-lse
// -> inputs 0..2 dead. Linear domain: K = exp(g - 8) (fp16, scale-invariant),
// u_i = 1/(K v)_i, v_j = 1/(K^T u)_j, out = K .* (u v^T).
//
// K lives ENTIRELY IN REGISTERS for the whole solve:
//   grid = 256 blocks (8 per batch) x 1024 threads, 1 block/CU (VGPR-capped).
//   wave owns 8 rows; lane owns col pairs j = c*128 + 2*lane (c = 0..7);
//   kr[8][8] __half2 = 64 VGPRs/thread = 256 KiB/CU = 64 MiB chip-wide.
// Row pass: wave-local shuffle reduce (lane cols x 64 lanes = all 1024 cols).
// Col pass: LDS reduce over 16 waves -> one atomicAdd per col per block ->
// 8-block arrival counter per (batch,iter) -> coherent readback.
// NO cooperative launch (not graph-capturable): plain launch; sync groups are
// 8 consecutive blocks; 1 block/CU at grid==CU-count makes deadlock unreachable,
// and the spin is bounded as insurance.
// Global traffic: read g once (134 MB) + write out once (134 MB) + ~3 MB/iter.
#define BB 32
#define NN 1024
#define SHIFT 8.0f
#define GS_ITERS 20

__global__ __launch_bounds__(1024, 4) void sinkhorn_persist(
    const float* __restrict__ g, float* __restrict__ out,
    float* __restrict__ colsum, int* __restrict__ cnt)
{
    const int b    = blockIdx.x >> 3;     // batch
    const int blk  = blockIdx.x & 7;      // row-chunk within batch (128 rows)
    const int wave = threadIdx.x >> 6;    // 0..15
    const int lane = threadIdx.x & 63;
    const int tid  = threadIdx.x;
    const int row0 = blk * 128 + wave * 8;

    const float* gb = g + ((size_t)b << 20);
    float* ob = out + ((size_t)b << 20);

    __shared__ float sm[16][1024];        // 64 KiB

    __half2 kr[8][8];                     // K fragment: 8 rows x 8 col-pairs
    float u[8];
    float vr[16];

    // ---- load g (float2), exp(g-SHIFT), pack fp16; fp32 row sums -> u ----
    #pragma unroll
    for (int p = 0; p < 8; ++p) {
        const float2* grow = (const float2*)(gb + (((size_t)(row0 + p)) << 10)) + lane;
        float s = 0.f;
        #pragma unroll
        for (int c = 0; c < 8; ++c) {
            float2 gg = grow[c * 64];                 // cols c*128 + 2*lane, +1
            float e0 = __expf(gg.x - SHIFT);
            float e1 = __expf(gg.y - SHIFT);
            s += e0 + e1;
            kr[p][c] = __floats2half2_rn(e0, e1);
        }
        #pragma unroll
        for (int off = 32; off; off >>= 1) s += __shfl_xor(s, off);
        u[p] = 1.0f / s;
    }

    #pragma unroll 1
    for (int it = 0; it < GS_ITERS; ++it) {
        // ---- col partials over this wave's 8 rows (register-local) ----
        float cs[16];
        #pragma unroll
        for (int c = 0; c < 16; ++c) cs[c] = 0.f;
        #pragma unroll
        for (int p = 0; p < 8; ++p) {
            const float up = u[p];
            #pragma unroll
            for (int c = 0; c < 8; ++c) {
                float2 f = __half22float2(kr[p][c]);
                cs[2*c]   = fmaf(f.x, up, cs[2*c]);
                cs[2*c+1] = fmaf(f.y, up, cs[2*c+1]);
            }
        }
        // LDS reduce across 16 waves (float2, 2-way bank alias = free)
        #pragma unroll
        for (int c = 0; c < 8; ++c)
            ((float2*)&sm[wave][0])[c * 64 + lane] = make_float2(cs[2*c], cs[2*c+1]);
        __syncthreads();

        float bp = 0.f;
        #pragma unroll
        for (int w = 0; w < 16; ++w) bp += sm[w][tid];
        float* csit = colsum + (((size_t)(b * GS_ITERS + it)) << 10);
        atomicAdd(csit + tid, bp);        // device-scope atomic (coherent)
        __syncthreads();                  // barrier drains vmcnt: adds complete

        // ---- 8-block arrival sync for this (batch, iter) ----
        if (tid == 0) {
            int* c8 = cnt + b * GS_ITERS + it;
            __hip_atomic_fetch_add(c8, 1, __ATOMIC_ACQ_REL, __HIP_MEMORY_SCOPE_AGENT);
            int spins = 0;
            while (__hip_atomic_load(c8, __ATOMIC_ACQUIRE, __HIP_MEMORY_SCOPE_AGENT) < 8) {
                __builtin_amdgcn_s_sleep(8);
                if (++spins > (1 << 22)) break;   // ~1s insurance: never hang
            }
        }
        __syncthreads();

        // coherent readback (agent-scope load bypasses stale L1), bcast via LDS
        float tot = __hip_atomic_load(csit + tid, __ATOMIC_RELAXED, __HIP_MEMORY_SCOPE_AGENT);
        sm[0][tid] = 1.0f / tot;
        __syncthreads();
        #pragma unroll
        for (int c = 0; c < 8; ++c) {
            float2 vv = ((const float2*)&sm[0][0])[c * 64 + lane];
            vr[2*c] = vv.x; vr[2*c+1] = vv.y;
        }

        // ---- row pass -> new u (skip after last col pass) ----
        if (it < GS_ITERS - 1) {
            #pragma unroll
            for (int p = 0; p < 8; ++p) {
                float s = 0.f;
                #pragma unroll
                for (int c = 0; c < 8; ++c) {
                    float2 f = __half22float2(kr[p][c]);
                    s = fmaf(f.x, vr[2*c],   s);
                    s = fmaf(f.y, vr[2*c+1], s);
                }
                #pragma unroll
                for (int off = 32; off; off >>= 1) s += __shfl_xor(s, off);
                u[p] = 1.0f / s;
            }
        }
        __syncthreads();                  // protect sm before next iter writes
    }

    // ---- out = K .* (u v^T), coalesced float2 stores ----
    #pragma unroll
    for (int p = 0; p < 8; ++p) {
        float2* orow = (float2*)(ob + (((size_t)(row0 + p)) << 10)) + lane;
        const float up = u[p];
        #pragma unroll
        for (int c = 0; c < 8; ++c) {
            float2 f = __half22float2(kr[p][c]);
            orow[c * 64] = make_float2(f.x * up * vr[2*c], f.y * up * vr[2*c+1]);
        }
    }
}

// ---------- fallback path (tiny ws, log-domain, kernel-per-step) ----------

template<bool USE_V>
__global__ __launch_bounds__(256) void row_step(const float* __restrict__ g,
                                                const float* __restrict__ v,
                                                float* __restrict__ t) {
    const int wave = threadIdx.x >> 6, lane = threadIdx.x & 63;
    const int row = blockIdx.x * 4 + wave;
    const int b = row >> 10;
    const float4* grow = (const float4*)(g + ((size_t)row << 10));
    const float4* vrow = (const float4*)(v + ((size_t)b << 10));
    float x[16];
    #pragma unroll
    for (int k = 0; k < 4; k++) {
        float4 gg = grow[lane + 64 * k];
        if (USE_V) {
            float4 vv = vrow[lane + 64 * k];
            x[4*k+0] = gg.x + vv.x; x[4*k+1] = gg.y + vv.y;
            x[4*k+2] = gg.z + vv.z; x[4*k+3] = gg.w + vv.w;
        } else {
            x[4*k+0] = gg.x; x[4*k+1] = gg.y; x[4*k+2] = gg.z; x[4*k+3] = gg.w;
        }
    }
    float m = -INFINITY;
    #pragma unroll
    for (int k = 0; k < 16; k++) m = fmaxf(m, x[k]);
    #pragma unroll
    for (int off = 32; off; off >>= 1) m = fmaxf(m, __shfl_xor(m, off));
    float s = 0.f;
    #pragma unroll
    for (int k = 0; k < 16; k++) s += __expf(x[k] - m);
    #pragma unroll
    for (int off = 32; off; off >>= 1) s += __shfl_xor(s, off);
    if (lane == 0) t[row] = -(m + __logf(s));
}

__global__ __launch_bounds__(256) void col_step(const float* __restrict__ g,
                                                const float* __restrict__ t,
                                                float* __restrict__ v) {
    const int b = blockIdx.x >> 4, tile = blockIdx.x & 15;
    const int tx = threadIdx.x & 63, ty = threadIdx.x >> 6;
    const int j = tile * 64 + tx;
    const float* gp = g + ((size_t)b << 20) + j;
    const float* tp = t + (b << 10);
    float m = -INFINITY, s = 0.f;
    for (int it = 0; it < 256; it += 8) {
        float xv[8];
        #pragma unroll
        for (int u2 = 0; u2 < 8; u2++) {
            int i = ((it + u2) << 2) + ty;
            xv[u2] = gp[(size_t)i << 10] + tp[i];
        }
        #pragma unroll
        for (int u2 = 0; u2 < 8; u2++) {
            float nm = fmaxf(m, xv[u2]);
            s = s * __expf(m - nm) + __expf(xv[u2] - nm);
            m = nm;
        }
    }
    __shared__ float sm[4][64];
    __shared__ float ss[4][64];
    sm[ty][tx] = m; ss[ty][tx] = s;
    __syncthreads();
    if (ty == 0) {
        float M = sm[0][tx], S = ss[0][tx];
        #pragma unroll
        for (int k = 1; k < 4; k++) {
            float mk = sm[k][tx], sk = ss[k][tx];
            float nm = fmaxf(M, mk);
            S = S * __expf(M - nm) + sk * __expf(mk - nm);
            M = nm;
        }
        v[(b << 10) + j] = -(M + __logf(S));
    }
}

__global__ __launch_bounds__(256) void finalize_k(const float* __restrict__ g,
                                                  const float* __restrict__ t,
                                                  const float* __restrict__ v,
                                                  float* __restrict__ out) {
    const size_t idx4 = (size_t)blockIdx.x * 256 + threadIdx.x;
    const size_t base = idx4 << 2;
    const int row = (int)(base >> 10), b = row >> 10;
    const int j = (int)(base & 1023);
    const float ti = t[row];
    float4 gg = ((const float4*)g)[idx4];
    float4 vv = ((const float4*)(v + ((size_t)b << 10)))[j >> 2];
    float4 o;
    o.x = __expf(gg.x + ti + vv.x);
    o.y = __expf(gg.y + ti + vv.y);
    o.z = __expf(gg.z + ti + vv.z);
    o.w = __expf(gg.w + ti + vv.w);
    ((float4*)out)[idx4] = o;
}

extern "C" void kernel_launch(void* const* d_in, const int* in_sizes, int n_in,
                              void* d_out, int out_size, void* d_ws, size_t ws_size,
                              hipStream_t stream) {
    const float* g = (const float*)d_in[3];   // gumbel noise; inputs 0..2 dead
    float* out = (float*)d_out;
    const size_t needCS  = (size_t)BB * GS_ITERS * NN * sizeof(float);  // 2.62 MB
    const size_t needCnt = (size_t)BB * GS_ITERS * sizeof(int);         // 2.5 KB

    if (ws_size >= needCS + needCnt) {
        float* colsum = (float*)d_ws;
        int* cnt = (int*)((char*)d_ws + needCS);
        hipMemsetAsync(d_ws, 0, needCS + needCnt, stream);
        sinkhorn_persist<<<BB * 8, 1024, 0, stream>>>(g, out, colsum, cnt);
    } else {
        float* t = (float*)d_ws;
        float* v = t + BB * NN;
        row_step<false><<<8192, 256, 0, stream>>>(g, nullptr, t);
        col_step<<<512, 256, 0, stream>>>(g, t, v);
        for (int it = 1; it < 20; it++) {
            row_step<true><<<8192, 256, 0, stream>>>(g, v, t);
            col_step<<<512, 256, 0, stream>>>(g, t, v);
        }
        finalize_k<<<32768, 256, 0, stream>>>(g, t, v, out);
    }
}